// Round 3
// baseline (176.173 us; speedup 1.0000x reference)
//
#include <hip/hip_runtime.h>
#include <hip/hip_bf16.h>

#define NL 4096   // 64*64 low-res pixels
#define HH 32
#define WH 32

typedef __attribute__((ext_vector_type(8))) short s8v;   // 8 bf16 MFMA A/B frag
typedef __attribute__((ext_vector_type(4))) short s4v;   // 4 bf16 (8B)
typedef __attribute__((ext_vector_type(4))) float f32x4; // MFMA C/D frag

static __device__ inline unsigned short f2bf(float x) {
  __hip_bfloat16 h = __float2bfloat16(x);   // RNE
  return *reinterpret_cast<unsigned short*>(&h);
}
static __device__ inline float bfbits2f(unsigned int lo16) {
  unsigned int u = lo16 << 16;
  return *reinterpret_cast<float*>(&u);
}

// ---------------------------------------------------------------------------
// Weight fp32 -> bf16 (packed): W1 65536 | W2 32768 | Wq 2048 | Wk 2048 |
// Wv 16384 | Woff 8192 | Wb 98304   (total 225280)
// ---------------------------------------------------------------------------
__global__ __launch_bounds__(256) void convert_weights_k(
    const float* __restrict__ w1, const float* __restrict__ w2,
    const float* __restrict__ wq, const float* __restrict__ wk,
    const float* __restrict__ wv, const float* __restrict__ woff,
    const float* __restrict__ wb, short* __restrict__ dst) {
  int i = blockIdx.x * 256 + threadIdx.x;
  const float* src; int off;
  if      (i <  65536) { src = w1;   off = 0; }
  else if (i <  98304) { src = w2;   off = 65536; }
  else if (i < 100352) { src = wq;   off = 98304; }
  else if (i < 102400) { src = wk;   off = 100352; }
  else if (i < 118784) { src = wv;   off = 102400; }
  else if (i < 126976) { src = woff; off = 118784; }
  else if (i < 225280) { src = wb;   off = 126976; }
  else return;
  dst[i] = (short)f2bf(src[i - off]);
}

// ---------------------------------------------------------------------------
// Fused: bilinear 2x upsample of high (c<256) + copy of low (c>=256),
// transposed to bf16 pixel-major xin[b][n][512].
// grid (64 n-tiles, 8 c-tiles, 2 b), block 256.
// ---------------------------------------------------------------------------
__global__ __launch_bounds__(256) void prep_k(const float* __restrict__ high,
                                              const float* __restrict__ low,
                                              short* __restrict__ xin) {
  const int b = blockIdx.z;
  const int n0 = blockIdx.x * 64, c0 = blockIdx.y * 64;
  __shared__ short lds[64][65];
  const int nl = threadIdx.x & 63, cl = threadIdx.x >> 6;

  if (c0 < 256) {
    // bilinear taps depend only on pixel
    int n = n0 + nl;
    int y = n >> 6, x = n & 63;
    float sx = x * 0.5f - 0.25f;
    float sy = y * 0.5f - 0.25f;
    float x0f = floorf(sx), y0f = floorf(sy);
    float wx = sx - x0f, wy = sy - y0f;
    int x0 = (int)x0f, y0 = (int)y0f;
    int x0c = min(WH - 1, max(0, x0)), x1c = min(WH - 1, max(0, x0 + 1));
    int y0c = min(HH - 1, max(0, y0)), y1c = min(HH - 1, max(0, y0 + 1));
    float w00 = (1.f - wy) * (1.f - wx), w01 = (1.f - wy) * wx;
    float w10 = wy * (1.f - wx),         w11 = wy * wx;
#pragma unroll
    for (int i = 0; i < 16; i++) {
      int c = c0 + cl + 4 * i;
      const float* f = high + ((size_t)b * 256 + c) * (HH * WH);
      float v = w00 * f[y0c * WH + x0c] + w01 * f[y0c * WH + x1c]
              + w10 * f[y1c * WH + x0c] + w11 * f[y1c * WH + x1c];
      lds[nl][cl + 4 * i] = (short)f2bf(v);
    }
  } else {
#pragma unroll
    for (int i = 0; i < 16; i++) {
      int c = c0 - 256 + cl + 4 * i;
      lds[nl][cl + 4 * i] = (short)f2bf(low[((size_t)b * 256 + c) * NL + n0 + nl]);
    }
  }
  __syncthreads();
  const int cc = threadIdx.x & 63, nr = threadIdx.x >> 6;
#pragma unroll
  for (int i = 0; i < 16; i++) {
    int n = n0 + nr + 4 * i;
    xin[((size_t)b * NL + n) * 512 + c0 + cc] = lds[nr + 4 * i][cc];
  }
}

// ---------------------------------------------------------------------------
// MFMA GEMM core: Y[n][o] = sum_k W[o][k]*X[n][k]. Wave tile 16n x (MF*16)m.
// Block = 4 waves stacked over n (64 n / block).
// MODE 0: bf16 pixel-major [n][M] | 1: f32 pixel-major [n][M]
// MODE 2: f32 channel-major [b][M][4096] + BN + ReLU
// ---------------------------------------------------------------------------
template <int M, int K1, int K2, int MF, int MODE>
__device__ __forceinline__ void gemm_core(
    const short* __restrict__ W, const float* __restrict__ bias,
    const short* __restrict__ B1, int sB1,
    const short* __restrict__ B2, int sB2,
    void* __restrict__ Yv,
    const float* __restrict__ gamma, const float* __restrict__ beta,
    const float* __restrict__ rmean, const float* __restrict__ rvar,
    int bx, int by) {
  constexpr int K = K1 + K2;
  const int tid = threadIdx.x;
  const int wave = tid >> 6, lane = tid & 63;
  const int quad = lane >> 4, id = lane & 15;
  const int n = bx * 64 + wave * 16 + id;     // this lane's pixel (B-frag row)
  const int m0 = by * (MF * 16);

  f32x4 acc[MF];
#pragma unroll
  for (int mf = 0; mf < MF; mf++) acc[mf] = (f32x4){0.f, 0.f, 0.f, 0.f};

  const short* ap[MF];
#pragma unroll
  for (int mf = 0; mf < MF; mf++)
    ap[mf] = W + (size_t)(m0 + mf * 16 + id) * K + quad * 8;
  const short* bp = B1 + (size_t)n * sB1 + quad * 8;

#pragma unroll
  for (int kk = 0; kk < K1; kk += 32) {
    s8v bfr = *(const s8v*)(bp + kk);
    s8v a[MF];
#pragma unroll
    for (int mf = 0; mf < MF; mf++) a[mf] = *(const s8v*)(ap[mf] + kk);
#pragma unroll
    for (int mf = 0; mf < MF; mf++)
      acc[mf] = __builtin_amdgcn_mfma_f32_16x16x32_bf16(a[mf], bfr, acc[mf], 0, 0, 0);
  }
  if constexpr (K2 > 0) {
    const short* bp2 = B2 + (size_t)n * sB2 + quad * 8;
#pragma unroll
    for (int kk = 0; kk < K2; kk += 32) {
      s8v bfr = *(const s8v*)(bp2 + kk);
      s8v a[MF];
#pragma unroll
      for (int mf = 0; mf < MF; mf++) a[mf] = *(const s8v*)(ap[mf] + K1 + kk);
#pragma unroll
      for (int mf = 0; mf < MF; mf++)
        acc[mf] = __builtin_amdgcn_mfma_f32_16x16x32_bf16(a[mf], bfr, acc[mf], 0, 0, 0);
    }
  }

#pragma unroll
  for (int mf = 0; mf < MF; mf++) {
    int mbase = m0 + mf * 16 + quad * 4;
    f32x4 v = acc[mf];
    if (bias) {
#pragma unroll
      for (int r = 0; r < 4; r++) v[r] += bias[mbase + r];
    }
    if constexpr (MODE == 0) {
      s4v o;
#pragma unroll
      for (int r = 0; r < 4; r++) o[r] = (short)f2bf(v[r]);
      *(s4v*)((short*)Yv + (size_t)n * M + mbase) = o;
    } else if constexpr (MODE == 1) {
      *(f32x4*)((float*)Yv + (size_t)n * M + mbase) = v;
    } else {
      int b = n >> 12, nlow = n & (NL - 1);
#pragma unroll
      for (int r = 0; r < 4; r++) {
        int o = mbase + r;
        float s  = gamma[o] * rsqrtf(rvar[o] + 1e-5f);
        float sh = beta[o] - rmean[o] * s;
        ((float*)Yv)[((size_t)b * M + o) * NL + nlow] =
            fmaxf(fmaf(v[r], s, sh), 0.f);
      }
    }
  }
}

// stage A: z=0 -> qf = W1 @ xin(512);  z=1 -> vf = W2 @ xin(:256)
__global__ __launch_bounds__(256) void stageA_k(
    const short* __restrict__ wc, const float* __restrict__ b1,
    const float* __restrict__ b2, const short* __restrict__ xin,
    short* __restrict__ qf, short* __restrict__ vf) {
  if (blockIdx.z == 0)
    gemm_core<128, 512, 0, 2, 0>(wc, b1, xin, 512, nullptr, 0, qf,
                                 nullptr, nullptr, nullptr, nullptr,
                                 blockIdx.x, blockIdx.y);
  else
    gemm_core<128, 256, 0, 2, 0>(wc + 65536, b2, xin, 512, nullptr, 0, vf,
                                 nullptr, nullptr, nullptr, nullptr,
                                 blockIdx.x, blockIdx.y);
}

// stage B: z=0 q(Wq@qf), z=1 k(Wk@vf), z=2 off(Woff@qf), z=3 v(Wv@vf)
__global__ __launch_bounds__(256) void stageB_k(
    const short* __restrict__ wc,
    const float* __restrict__ bq, const float* __restrict__ bk,
    const float* __restrict__ bv, const float* __restrict__ boff,
    const short* __restrict__ qf, const short* __restrict__ vf,
    float* __restrict__ q_t, float* __restrict__ k_t,
    float* __restrict__ off_t, short* __restrict__ v_t) {
  int z = blockIdx.z, by = blockIdx.y;
  if (z == 0) {
    if (by) return;
    gemm_core<16, 128, 0, 1, 1>(wc + 98304, bq, qf, 128, nullptr, 0, q_t,
                                nullptr, nullptr, nullptr, nullptr, blockIdx.x, 0);
  } else if (z == 1) {
    if (by) return;
    gemm_core<16, 128, 0, 1, 1>(wc + 100352, bk, vf, 128, nullptr, 0, k_t,
                                nullptr, nullptr, nullptr, nullptr, blockIdx.x, 0);
  } else if (z == 2) {
    if (by > 1) return;
    gemm_core<64, 128, 0, 2, 1>(wc + 118784, boff, qf, 128, nullptr, 0, off_t,
                                nullptr, nullptr, nullptr, nullptr, blockIdx.x, by);
  } else {
    gemm_core<128, 128, 0, 2, 0>(wc + 102400, bv, vf, 128, nullptr, 0, v_t,
                                 nullptr, nullptr, nullptr, nullptr, blockIdx.x, by);
  }
}

// final: out = ReLU(BN(Wb @ [attn(128); xin_high(256)]))
__global__ __launch_bounds__(256) void finalg_k(
    const short* __restrict__ wc, const short* __restrict__ attn_t,
    const short* __restrict__ xin, float* __restrict__ out,
    const float* __restrict__ gamma, const float* __restrict__ beta,
    const float* __restrict__ rmean, const float* __restrict__ rvar) {
  gemm_core<256, 128, 256, 2, 2>(wc + 126976, nullptr, attn_t, 128, xin, 512,
                                 out, gamma, beta, rmean, rvar,
                                 blockIdx.x, blockIdx.y);
}

// ---------------------------------------------------------------------------
// Deformable point-sampling attention. One wave per query.
// q_t/k_t [bn][16] f32, off_t [bn][64] f32, v_t [bn][128] bf16
// out attn_t [bn][128] bf16
// ---------------------------------------------------------------------------
__global__ __launch_bounds__(256) void attn_k(
    const float* __restrict__ q_t, const float* __restrict__ k_t,
    const short* __restrict__ v_t, const float* __restrict__ off_t,
    short* __restrict__ out) {
  const int lane = threadIdx.x;                // 0..63
  const int wav  = threadIdx.y;                // 0..3
  const int qidx = blockIdx.x * 4 + wav;
  const int b = qidx >> 12;
  const int n = qidx & (NL - 1);
  const int qy = n >> 6, qx = n & 63;

  __shared__ float s_w[4][32][4];
  __shared__ int   s_i[4][32][4];

  const float* qp = q_t + (size_t)qidx * 16;
  float qreg[16];
#pragma unroll
  for (int i = 0; i < 16; i += 4) {
    float4 t = *(const float4*)(qp + i);
    qreg[i] = t.x; qreg[i + 1] = t.y; qreg[i + 2] = t.z; qreg[i + 3] = t.w;
  }

  const int p = lane >> 1;
  const int h = lane & 1;
  float2 dxy = *(const float2*)(off_t + (size_t)qidx * 64 + 2 * p);
  float sx = (float)qx + dxy.x;
  float sy = (float)qy + dxy.y;
  float x0f = floorf(sx), y0f = floorf(sy);
  float wx = sx - x0f, wy = sy - y0f;
  int x0i = (int)x0f, y0i = (int)y0f;
  int x0 = min(63, max(0, x0i)), x1 = min(63, max(0, x0i + 1));
  int y0 = min(63, max(0, y0i)), y1 = min(63, max(0, y0i + 1));

  int   yr  = h ? y1 : y0;
  float wyr = h ? wy : (1.f - wy);
  int   pa = yr * 64 + x0, pb = yr * 64 + x1;
  float wa = wyr * (1.f - wx), wb = wyr * wx;

  const float* kb = k_t + (size_t)b * NL * 16;
  float da = 0.f, db = 0.f;
  {
    const float* ka = kb + (size_t)pa * 16;
    const float* kc = kb + (size_t)pb * 16;
#pragma unroll
    for (int i = 0; i < 16; i += 4) {
      float4 a4 = *(const float4*)(ka + i);
      float4 c4 = *(const float4*)(kc + i);
      da = fmaf(qreg[i], a4.x, da); da = fmaf(qreg[i + 1], a4.y, da);
      da = fmaf(qreg[i + 2], a4.z, da); da = fmaf(qreg[i + 3], a4.w, da);
      db = fmaf(qreg[i], c4.x, db); db = fmaf(qreg[i + 1], c4.y, db);
      db = fmaf(qreg[i + 2], c4.z, db); db = fmaf(qreg[i + 3], c4.w, db);
    }
  }
  float part = wa * da + wb * db;
  part += __shfl_xor(part, 1, 64);
  float logit = part * 0.25f;

  float m = logit;
#pragma unroll
  for (int s = 32; s > 0; s >>= 1) m = fmaxf(m, __shfl_xor(m, s, 64));
  float e = __expf(logit - m);
  float ssum = e;
#pragma unroll
  for (int s = 32; s > 0; s >>= 1) ssum += __shfl_xor(ssum, s, 64);
  float a = e * 2.f / ssum;     // ssum double-counts each point

  // fold softmax weight into tap weights
  s_w[wav][p][2 * h + 0] = a * wa;
  s_w[wav][p][2 * h + 1] = a * wb;
  s_i[wav][p][2 * h + 0] = pa;
  s_i[wav][p][2 * h + 1] = pb;
  __syncthreads();

  const short* vb = v_t + (size_t)b * NL * 128;
  const int c = 2 * lane;
  float o0 = 0.f, o1 = 0.f;
  for (int pp = 0; pp < 32; pp++) {
#pragma unroll
    for (int t = 0; t < 4; t++) {
      float w  = s_w[wav][pp][t];
      int  pix = s_i[wav][pp][t];
      unsigned int u = *(const unsigned int*)(vb + (size_t)pix * 128 + c);
      o0 = fmaf(w, bfbits2f(u & 0xffffu), o0);
      o1 = fmaf(w, bfbits2f(u >> 16), o1);
    }
  }
  unsigned int pk = (unsigned int)f2bf(o0) | ((unsigned int)f2bf(o1) << 16);
  *(unsigned int*)(out + (size_t)qidx * 128 + c) = pk;
}

// ---------------------------------------------------------------------------
extern "C" void kernel_launch(void* const* d_in, const int* in_sizes, int n_in,
                              void* d_out, int out_size, void* d_ws, size_t ws_size,
                              hipStream_t stream) {
  const float* low   = (const float*)d_in[0];
  const float* high  = (const float*)d_in[1];
  const float* W1    = (const float*)d_in[2];
  const float* b1    = (const float*)d_in[3];
  const float* W2    = (const float*)d_in[4];
  const float* b2    = (const float*)d_in[5];
  const float* Wq    = (const float*)d_in[6];
  const float* bq    = (const float*)d_in[7];
  const float* Wk    = (const float*)d_in[8];
  const float* bk    = (const float*)d_in[9];
  const float* Wv    = (const float*)d_in[10];
  const float* bv    = (const float*)d_in[11];
  const float* Woff  = (const float*)d_in[12];
  const float* boff  = (const float*)d_in[13];
  const float* Wb    = (const float*)d_in[14];
  const float* gamma = (const float*)d_in[15];
  const float* beta  = (const float*)d_in[16];
  const float* rmean = (const float*)d_in[17];
  const float* rvar  = (const float*)d_in[18];
  float* out = (float*)d_out;

  // workspace layout (shorts / floats)
  short* xin    = (short*)d_ws;            // [2][4096][512]  bf16
  short* qf_t   = xin + 4194304;           // [2][4096][128]
  short* vf_t   = qf_t + 1048576;          // [2][4096][128]
  short* v_t    = vf_t + 1048576;          // [2][4096][128]
  short* attn_t = v_t + 1048576;           // [2][4096][128]
  short* wc     = attn_t + 1048576;        // 225,280 bf16
  float* q_t    = (float*)(wc + 225280);   // [2][4096][16] f32
  float* k_t    = q_t + 131072;
  float* off_t  = k_t + 131072;            // [2][4096][64] f32

  convert_weights_k<<<880, 256, 0, stream>>>(W1, W2, Wq, Wk, Wv, Woff, Wb, wc);
  prep_k<<<dim3(64, 8, 2), 256, 0, stream>>>(high, low, xin);
  stageA_k<<<dim3(128, 4, 2), 256, 0, stream>>>(wc, b1, b2, xin, qf_t, vf_t);
  stageB_k<<<dim3(128, 4, 4), 256, 0, stream>>>(wc, bq, bk, bv, boff,
                                                qf_t, vf_t, q_t, k_t, off_t, v_t);
  attn_k<<<2048, dim3(64, 4), 0, stream>>>(q_t, k_t, v_t, off_t, attn_t);
  finalg_k<<<dim3(128, 8), 256, 0, stream>>>(wc, attn_t, xin, out,
                                             gamma, beta, rmean, rvar);
}